// Round 17
// baseline (408.766 us; speedup 1.0000x reference)
//
#include <hip/hip_runtime.h>

typedef unsigned short u16;
typedef unsigned int u32;
typedef __attribute__((ext_vector_type(8))) _Float16 half8;
typedef __attribute__((ext_vector_type(2))) __fp16 fp16x2;
typedef __attribute__((ext_vector_type(4))) float floatx4;

#define E_TOTAL 65536

__device__ __forceinline__ u32 pk16(float x0, float x1) {
    union { fp16x2 h; u32 u; } c;
    c.h = __builtin_amdgcn_cvt_pkrtz(x0, x1);
    return c.u;
}
union Frag8h { u32 u[4]; half8 v; };

// ws layout (floats): [0:6144] = 8 replicated 768-slot stat-bin arrays
// (replica r at [r*768, r*768+768)); ints [6144:6176] = binv.

// ---------------- Init: zero stat replicas + probe MFMA k-pairing (fused) ----------
__global__ __launch_bounds__(1024) void k_init(float* __restrict__ ws, int* __restrict__ binv) {
    const int tid = threadIdx.x;
    for (int i = tid; i < 6144; i += 1024) ws[i] = 0.0f;
    if (tid < 64) {
        const int lane = tid;
        const int q = lane >> 4;
        if (lane < 32) binv[lane] = lane;    // default identity (safety)
        half8 bfr;
        #pragma unroll
        for (int j = 0; j < 8; ++j) bfr[j] = (_Float16)(float)(q*8 + j + 1);
        #pragma unroll
        for (int s = 0; s < 32; ++s) {
            const int qa = s >> 3, ja = s & 7;
            half8 afr;
            #pragma unroll
            for (int j = 0; j < 8; ++j) afr[j] = (_Float16)0.0f;
            if (q == qa) afr[ja] = (_Float16)1.0f;
            floatx4 dc = {0.0f, 0.0f, 0.0f, 0.0f};
            dc = __builtin_amdgcn_mfma_f32_16x16x32_f16(afr, bfr, dc, 0, 0, 0);
            if (lane == 0) {
                const int sB = (int)(dc[0] + 0.5f) - 1;
                if (sB >= 0 && sB < 32) binv[sB] = s;
            }
        }
    }
}

// ---------------- Kernel 1: heavy conv (R15-verbatim loop) + low-contention stats ---
// Loop structure identical to the measured-307us R15 kernel (single sh_wt, 2 barriers
// per chunk, register prefetch). Stats folded into the epilogue with 8-way replicated
// global bins (replica = blockIdx&7) to avoid R16's atomic-contention regression.
__global__ __launch_bounds__(256) void k_edge_heavy(
    const float* __restrict__ node_fea, const float* __restrict__ edge_attr,
    const int* __restrict__ edge_index, const int* __restrict__ xsp,
    const float* __restrict__ w_rh, const float* __restrict__ b_rh,
    const float* __restrict__ w_ro, const float* __restrict__ b_ro,
    const float* __restrict__ w_pre, const float* __restrict__ b_pre,
    const float* __restrict__ w_sc, const float* __restrict__ w_post_s,
    const float* __restrict__ b_post_s, const float* __restrict__ w_post_v,
    const int* __restrict__ binv, const int* __restrict__ batch,
    float* __restrict__ ws_stats,
    float* __restrict__ out)
{
    __shared__ __align__(16) float sh_wt[32][130];   // 16640 B; prologue overlays here
    __shared__ float sh_sin[32][80];
    __shared__ float sh_vl[32][3][32];
    __shared__ float sh_acc[32][56];
    __shared__ float sh_y1[32][4];
    __shared__ int   sh_kmap[32];

    // Overlay (all dead before first sh_wt write; mutually disjoint):
    u16*   a_rbf = (u16*)&sh_wt[0][0];                     // [0,8192) B
    u16*   a_h   = (u16*)((char*)&sh_wt[0][0] + 8192);     // [8192,12288) B
    float* es0f  = (float*)((char*)&sh_wt[0][0] + 12288);  // [12288,14336) B

    const int tid = threadIdx.x;
    const int ed = tid >> 4, l16 = tid & 15;
    const int lane = tid & 63, w = tid >> 6;
    const int quad = lane >> 4, l15 = lane & 15;
    const int e0 = blockIdx.x * 32 + ed;
    const int e1 = e0 + 16;

    if (tid < 32) sh_kmap[tid] = binv[tid];

    const int ni0 = edge_index[e0], nj0 = edge_index[E_TOTAL + e0];
    const int ni1 = edge_index[e1], nj1 = edge_index[E_TOTAL + e1];
    const float4 ea0 = *(const float4*)(edge_attr + 4*e0);
    const float4 ea1 = *(const float4*)(edge_attr + 4*e1);
    const float d0 = ea0.x, d1 = ea1.x;
    {
        const float invn0 = 1.0f / (sqrtf(ea0.y*ea0.y + ea0.z*ea0.z + ea0.w*ea0.w) + 1e-12f);
        const float invn1 = 1.0f / (sqrtf(ea1.y*ea1.y + ea1.z*ea1.z + ea1.w*ea1.w) + 1e-12f);
        if (l16 == 0) {
            sh_y1[ed][0]    = 1.7320508075688772f * ea0.y * invn0;
            sh_y1[ed][1]    = 1.7320508075688772f * ea0.z * invn0;
            sh_y1[ed][2]    = 1.7320508075688772f * ea0.w * invn0;
            sh_y1[16+ed][0] = 1.7320508075688772f * ea1.y * invn1;
            sh_y1[16+ed][1] = 1.7320508075688772f * ea1.z * invn1;
            sh_y1[16+ed][2] = 1.7320508075688772f * ea1.w * invn1;
        }
    }

    // rbf -> fp16 A-fragments for both groups (into overlay)
    const float C128 = -0.5f * (127.0f/6.0f) * (127.0f/6.0f);
    const float S128 = 6.0f/127.0f;
    {
        Frag8h t0, t1;
        #pragma unroll
        for (int r2 = 0; r2 < 4; ++r2) {
            const int b0i = l16*8 + 2*r2;
            const float u0 = d0 - S128 * (float)b0i;
            const float u1 = d0 - S128 * (float)(b0i + 1);
            const float v0 = d1 - S128 * (float)b0i;
            const float v1 = d1 - S128 * (float)(b0i + 1);
            t0.u[r2] = pk16(expf(C128*u0*u0), expf(C128*u1*u1));
            t1.u[r2] = pk16(expf(C128*v0*v0), expf(C128*v1*v1));
        }
        *(half8*)&a_rbf[(l16*16 + ed)*8]        = t0.v;
        *(half8*)&a_rbf[2048 + (l16*16 + ed)*8] = t1.v;
    }
    {
        const float t0 = d0 - 0.4f * (float)l16;
        const float t1 = d1 - 0.4f * (float)l16;
        es0f[ed*16 + l16]      = expf(-3.125f * t0 * t0);
        es0f[(16+ed)*16 + l16] = expf(-3.125f * t1 * t1);
    }

    const float rs80 = 0.11180339887498949f;
    const float rs32 = 0.17677669529663689f;
    {
        const float* fi = node_fea + (size_t)ni0 * 80;
        const float* fj = node_fea + (size_t)nj0 * 80;
        sh_sin[ed][2*l16+0]    = fi[2*l16+0] * rs80;
        sh_sin[ed][2*l16+1]    = fi[2*l16+1] * rs80;
        sh_sin[ed][32+2*l16+0] = fj[2*l16+0] * rs80;
        sh_sin[ed][32+2*l16+1] = fj[2*l16+1] * rs80;
        #pragma unroll
        for (int c = 0; c < 3; ++c) {
            sh_vl[ed][c][l16]      = fi[32 + 3*l16 + c] * rs32;
            sh_vl[ed][c][16 + l16] = fj[32 + 3*l16 + c] * rs32;
        }
    }
    {
        const float* fi = node_fea + (size_t)ni1 * 80;
        const float* fj = node_fea + (size_t)nj1 * 80;
        sh_sin[16+ed][2*l16+0]    = fi[2*l16+0] * rs80;
        sh_sin[16+ed][2*l16+1]    = fi[2*l16+1] * rs80;
        sh_sin[16+ed][32+2*l16+0] = fj[2*l16+0] * rs80;
        sh_sin[16+ed][32+2*l16+1] = fj[2*l16+1] * rs80;
        #pragma unroll
        for (int c = 0; c < 3; ++c) {
            sh_vl[16+ed][c][l16]      = fi[32 + 3*l16 + c] * rs32;
            sh_vl[16+ed][c][16 + l16] = fj[32 + 3*l16 + c] * rs32;
        }
    }
    for (int s = tid; s < 32*56; s += 256) (&sh_acc[0][0])[s] = 0.0f;
    __syncthreads();

    int km[8];
    u32 voff0[8], voff1[8];
    #pragma unroll
    for (int j = 0; j < 8; ++j) {
        km[j] = sh_kmap[quad*8 + j];
        voff0[j] = (u32)(km[j] * 3840 + l15);
        voff1[j] = voff0[j] + 32u * 3840u;
    }

    // edge_s + sc for both edges (reads es0f overlay)
    float my_sc0, my_sc1;
    {
        const int o = l16;
        float es0v = b_pre[o], sc0 = 0.0f;
        float es1v = b_pre[o], sc1 = 0.0f;
        const int p0 = 4*xsp[ni0] + xsp[nj0];
        const int p1 = 4*xsp[ni1] + xsp[nj1];
        #pragma unroll
        for (int i = 0; i < 16; ++i) {
            const float g0 = es0f[ed*16 + i];
            const float g1 = es0f[(16+ed)*16 + i];
            es0v += g0 * w_pre[i*16 + o];
            es1v += g1 * w_pre[i*16 + o];
            sc0  += g0 * w_sc[(i*16 + p0)*16 + o];
            sc1  += g1 * w_sc[(i*16 + p1)*16 + o];
        }
        sh_sin[ed][64 + o]    = es0v * rs80;
        sh_sin[16+ed][64 + o] = es1v * rs80;
        my_sc0 = sc0 * 0.0625f;
        my_sc1 = sc1 * 0.0625f;
    }

    // h = silu(rbf @ w_rh + b_rh), both groups share B  (reads a_rbf, writes a_h)
    {
        floatx4 h0 = {0.0f, 0.0f, 0.0f, 0.0f};
        floatx4 h1 = {0.0f, 0.0f, 0.0f, 0.0f};
        #pragma unroll
        for (int kk = 0; kk < 4; ++kk) {
            const half8 ag0 = *(const half8*)&a_rbf[((kk*4 + quad)*16 + l15)*8];
            const half8 ag1 = *(const half8*)&a_rbf[2048 + ((kk*4 + quad)*16 + l15)*8];
            Frag8h bh;
            #pragma unroll
            for (int jj = 0; jj < 4; ++jj) {
                const float x0 = w_rh[(size_t)(kk*32 + km[2*jj+0])*64 + w*16 + l15];
                const float x1 = w_rh[(size_t)(kk*32 + km[2*jj+1])*64 + w*16 + l15];
                bh.u[jj] = pk16(x0, x1);
            }
            h0 = __builtin_amdgcn_mfma_f32_16x16x32_f16(ag0, bh.v, h0, 0, 0, 0);
            h1 = __builtin_amdgcn_mfma_f32_16x16x32_f16(ag1, bh.v, h1, 0, 0, 0);
        }
        const int hn = w*16 + l15;
        const float bb = b_rh[hn];
        const int k8 = hn >> 3, j2 = hn & 7;
        #pragma unroll
        for (int r = 0; r < 4; ++r) {
            const int m = quad*4 + r;
            {
                const float x = h0[r] + bb;
                const float s = x / (1.0f + expf(-x));
                union { _Float16 h; u16 u; } cv; cv.h = (_Float16)s;
                a_h[(k8*16 + m)*8 + j2] = cv.u;
            }
            {
                const float x = h1[r] + bb;
                const float s = x / (1.0f + expf(-x));
                union { _Float16 h; u16 u; } cv; cv.h = (_Float16)s;
                a_h[1024 + (k8*16 + m)*8 + j2] = cv.u;
            }
        }
    }
    __syncthreads();

    // A-fragments into registers (overlay dies after this point)
    const half8 a0g0 = *(const half8*)&a_h[((0*4 + quad)*16 + l15)*8];
    const half8 a1g0 = *(const half8*)&a_h[((1*4 + quad)*16 + l15)*8];
    const half8 a0g1 = *(const half8*)&a_h[1024 + ((0*4 + quad)*16 + l15)*8];
    const half8 a1g1 = *(const half8*)&a_h[1024 + ((1*4 + quad)*16 + l15)*8];

    // Prefetch buffer: pf[ct*16 + {0..7}]=khalf0, pf[ct*16+8+{0..7}]=khalf1 (static idx)
    float pf[32];
    float pbias[2];
    #pragma unroll
    for (int ct = 0; ct < 2; ++ct) {
        const int sgct = __builtin_amdgcn_readfirstlane(w*2 + ct);   // chunk 0
        const float* bp = w_ro + sgct*16;
        #pragma unroll
        for (int j = 0; j < 8; ++j) {
            pf[ct*16 + j]     = bp[voff0[j]];
            pf[ct*16 + 8 + j] = bp[voff1[j]];
        }
        pbias[ct] = b_ro[sgct*16 + l15];
    }

    // -------- main loop: 30 chunks x 128 cols; loads for ch+1 fly under consumers ----
    for (int ch = 0; ch < 30; ++ch) {
        const int coff = ch * 128;
        floatx4 acc0[2], acc1[2];
        float bias[2];
        #pragma unroll
        for (int ct = 0; ct < 2; ++ct) {
            Frag8h b0, b1;
            #pragma unroll
            for (int jj = 0; jj < 4; ++jj) {
                b0.u[jj] = pk16(pf[ct*16 + 2*jj],     pf[ct*16 + 2*jj+1]);
                b1.u[jj] = pk16(pf[ct*16 + 8 + 2*jj], pf[ct*16 + 8 + 2*jj+1]);
            }
            floatx4 a = {0.0f, 0.0f, 0.0f, 0.0f};
            a = __builtin_amdgcn_mfma_f32_16x16x32_f16(a0g0, b0.v, a, 0, 0, 0);
            a = __builtin_amdgcn_mfma_f32_16x16x32_f16(a1g0, b1.v, a, 0, 0, 0);
            acc0[ct] = a;
            floatx4 c = {0.0f, 0.0f, 0.0f, 0.0f};
            c = __builtin_amdgcn_mfma_f32_16x16x32_f16(a0g1, b0.v, c, 0, 0, 0);
            c = __builtin_amdgcn_mfma_f32_16x16x32_f16(a1g1, b1.v, c, 0, 0, 0);
            acc1[ct] = c;
            bias[ct] = pbias[ct];
        }
        __syncthreads();   // previous chunk's consumers done with sh_wt
        #pragma unroll
        for (int ct = 0; ct < 2; ++ct) {
            const int col = w*32 + ct*16 + l15;
            #pragma unroll
            for (int r = 0; r < 4; ++r) {
                sh_wt[quad*4 + r][col]      = acc0[ct][r] + bias[ct];
                sh_wt[16 + quad*4 + r][col] = acc1[ct][r] + bias[ct];
            }
        }
        __syncthreads();

        // prefetch chunk ch+1 (issued AFTER the drain; in flight during consumers)
        if (ch < 29) {
            #pragma unroll
            for (int ct = 0; ct < 2; ++ct) {
                const int sgct = __builtin_amdgcn_readfirstlane((ch+1)*8 + w*2 + ct);
                const float* bp = w_ro + sgct*16;
                #pragma unroll
                for (int j = 0; j < 8; ++j) {
                    pf[ct*16 + j]     = bp[voff0[j]];
                    pf[ct*16 + 8 + j] = bp[voff1[j]];
                }
                pbias[ct] = b_ro[sgct*16 + l15];
            }
        }

        if (ch < 15) {          // w1: cols 0..1920, 24-wide -> s_conv (dynamic bounds)
            for (int idx = tid; idx < 768; idx += 256) {
                const int eo = idx / 24, o = idx % 24;
                const int i0 = (coff > o) ? (coff - o + 23) / 24 : 0;
                int i1 = (coff + 128 - o + 23) / 24; if (i1 > 80) i1 = 80;
                float a = 0.0f;
                for (int i = i0; i < i1; ++i)
                    a += sh_sin[eo][i] * sh_wt[eo][i*24 + o - coff];
                sh_acc[eo][o] += a;
            }
        } else if (ch < 20) {   // w2: 16 rows x 8 per chunk (STATIC)
            const int ib = (ch - 15) * 16;
            for (int idx = tid; idx < 256; idx += 256) {
                const int eo = idx >> 3, o = idx & 7;
                float a = 0.0f;
                #pragma unroll
                for (int i = 0; i < 16; ++i)
                    a += sh_sin[eo][ib + i] * sh_wt[eo][i*8 + o];
                sh_acc[eo][24 + o] += a;
            }
        } else if (ch < 22) {   // w3: 16 rows x 8 per chunk, left = v_in[:,c] (STATIC)
            const int ib = (ch - 20) * 16;
            for (int idx = tid; idx < 768; idx += 256) {
                const int eo = idx / 24, rem = idx % 24;
                const int o = rem / 3, cc = rem % 3;
                float a = 0.0f;
                #pragma unroll
                for (int i = 0; i < 16; ++i)
                    a += sh_vl[eo][cc][ib + i] * sh_wt[eo][i*8 + o];
                sh_acc[eo][32 + o*3 + cc] += a;
            }
        } else if (ch < 28) {   // w4: cols 2816..3584, 24-wide, q inline (dynamic)
            const int rel = coff - 2816;
            for (int idx = tid; idx < 768; idx += 256) {
                const int eo = idx / 24, o = idx % 24;
                const int i0 = (rel > o) ? (rel - o + 23) / 24 : 0;
                int i1 = (rel + 128 - o + 23) / 24; if (i1 > 32) i1 = 32;
                const float Ya = sh_y1[eo][0], Yb = sh_y1[eo][1], Yc = sh_y1[eo][2];
                float a = 0.0f;
                for (int i = i0; i < i1; ++i) {
                    const float qv = sh_vl[eo][0][i]*Ya + sh_vl[eo][1][i]*Yb
                                   + sh_vl[eo][2][i]*Yc;
                    a += qv * sh_wt[eo][i*24 + o - rel];
                }
                sh_acc[eo][o] += a * 0.57735026918962573f;
            }
        } else {                // w5: 16 rows x 8 per chunk, cross inline (STATIC)
            const int ib = (ch - 28) * 16;
            for (int idx = tid; idx < 768; idx += 256) {
                const int eo = idx / 24, rem = idx % 24;
                const int o = rem / 3, cc = rem % 3;
                const int c1 = (cc < 2) ? cc + 1 : 0;
                const int c2 = (c1 < 2) ? c1 + 1 : 0;
                const float Yp = sh_y1[eo][c2];
                const float Ym = sh_y1[eo][c1];
                float a = 0.0f;
                #pragma unroll
                for (int i = 0; i < 16; ++i)
                    a += (sh_vl[eo][c1][ib+i]*Yp - sh_vl[eo][c2][ib+i]*Ym) * sh_wt[eo][i*8 + o];
                sh_acc[eo][32 + o*3 + cc] += a * 0.70710678118654746f;
            }
        }
    }
    __syncthreads();

    // -------- epilogue: outputs + folded stats (LDS bins overlay; 8-way replica) ----
    float* bins = &sh_wt[0][0];   // 768 floats; sh_wt dead after final barrier
    for (int s = tid; s < 768; s += 256) bins[s] = 0.0f;
    __syncthreads();

    const int gi0 = batch[ni0];
    const int gi1 = batch[ni1];
    #pragma unroll
    for (int g = 0; g < 2; ++g) {
        const int er = g*16 + ed;
        const int e  = (g == 0) ? e0 : e1;
        const int gi = (g == 0) ? gi0 : gi1;
        const float msc = (g == 0) ? my_sc0 : my_sc1;
        {
            const int o = l16;
            float a = b_post_s[o] + msc;
            #pragma unroll
            for (int i = 0; i < 16; ++i) {
                const float sv = sh_acc[er][i];
                a += (sv / (1.0f + expf(-sv))) * w_post_s[i*16 + o];
            }
            out[(size_t)e*40 + o] = a;
            atomicAdd(&bins[gi*48 + o], a);
            atomicAdd(&bins[gi*48 + 16 + o], a*a);
            if (o == 0) atomicAdd(&bins[gi*48 + 40], 1.0f);
        }
        if (l16 < 8) {
            const int o = l16;
            const float Ya = sh_y1[er][0], Yb = sh_y1[er][1], Yc = sh_y1[er][2];
            float r0 = 0.0f, r1 = 0.0f, r2 = 0.0f;
            #pragma unroll
            for (int i = 0; i < 8; ++i) {
                const float gt = 1.0f / (1.0f + expf(-sh_acc[er][16 + i]));
                const float a2 = sh_acc[er][24 + i];
                const float ww = w_post_v[i*8 + o];
                r0 += (a2*Ya + sh_acc[er][32 + i*3 + 0]) * gt * ww;
                r1 += (a2*Yb + sh_acc[er][32 + i*3 + 1]) * gt * ww;
                r2 += (a2*Yc + sh_acc[er][32 + i*3 + 2]) * gt * ww;
            }
            out[(size_t)e*40 + 16 + o*3 + 0] = r0;
            out[(size_t)e*40 + 16 + o*3 + 1] = r1;
            out[(size_t)e*40 + 16 + o*3 + 2] = r2;
            atomicAdd(&bins[gi*48 + 32 + o], r0*r0 + r1*r1 + r2*r2);
        }
    }
    __syncthreads();
    {
        float* rep = ws_stats + (blockIdx.x & 7) * 768;   // 8-way replicated targets
        for (int s = tid; s < 768; s += 256) {
            const float x = bins[s];
            if (x != 0.0f) atomicAdd(&rep[s], x);
        }
    }
}

// ---------------- Kernel 4: stats-finalize (sums 8 replicas) + LN + projections -----
__global__ __launch_bounds__(256) void k_edge_final(
    float* buf, const float* __restrict__ ws,
    const float* __restrict__ edge_attr, const int* __restrict__ edge_index,
    const int* __restrict__ batch,
    const float* __restrict__ ln_w_s, const float* __restrict__ ln_b_s,
    const float* __restrict__ ln_w_v, const float* __restrict__ w_skip,
    const float* __restrict__ w_edge_s, const float* __restrict__ b_edge_s,
    const float* __restrict__ w_edge_v)
{
    __shared__ float sh_mu[16][16];
    __shared__ float sh_is[16], sh_iv[16];
    __shared__ float sh_lws[16], sh_lbs[16], sh_lwv[8];
    __shared__ float sh_skip[16][16], sh_wes[16][16], sh_bes[16], sh_wev[8][8];
    const int tid = threadIdx.x;
    if (tid < 16) {
        const int g = tid;
        float sums[41];   // 16 mu-sums, 16 sq-sums, 8 v-sums, 1 cnt — summed replicas
        #pragma unroll
        for (int k = 0; k < 41; ++k) sums[k] = 0.0f;
        for (int r = 0; r < 8; ++r) {
            const float* rep = ws + r*768 + g*48;
            for (int chn = 0; chn < 16; ++chn) { sums[chn] += rep[chn]; sums[16+chn] += rep[16+chn]; }
            for (int o = 0; o < 8; ++o) sums[32+o] += rep[32+o];
            sums[40] += rep[40];
        }
        float cnt = sums[40]; if (cnt < 1.0f) cnt = 1.0f;
        const float ic = 1.0f / cnt;
        float vs = 0.0f;
        for (int chn = 0; chn < 16; ++chn) {
            const float mu = sums[chn] * ic;
            sh_mu[g][chn] = mu;
            vs += sums[16+chn] * ic - mu * mu;
        }
        if (vs < 0.0f) vs = 0.0f;
        sh_is[g] = 1.0f / sqrtf(vs * (1.0f/16.0f) + 1e-5f);
        float vv = 0.0f;
        for (int o = 0; o < 8; ++o) vv += sums[32+o];
        vv = vv * ic * (1.0f/3.0f) * (1.0f/8.0f);
        sh_iv[g] = 1.0f / sqrtf(vv + 1e-5f);
    }
    sh_skip[tid >> 4][tid & 15] = w_skip[tid];
    sh_wes[tid >> 4][tid & 15]  = w_edge_s[tid];
    if (tid < 16) {
        sh_lws[tid] = ln_w_s[tid];
        sh_lbs[tid] = ln_b_s[tid];
        sh_bes[tid] = b_edge_s[tid];
    }
    if (tid < 8)  sh_lwv[tid] = ln_w_v[tid];
    if (tid < 64) sh_wev[tid >> 3][tid & 7] = w_edge_v[tid];
    __syncthreads();

    const int e = blockIdx.x * 256 + tid;
    const int g = batch[edge_index[e]];
    const float d = edge_attr[4*e];
    float es0[16];
    #pragma unroll
    for (int b = 0; b < 16; ++b) {
        const float t = d - 0.4f * (float)b;
        es0[b] = expf(-3.125f * t * t);
    }
    float p[40];
    float* pb = buf + (size_t)e * 40;
    #pragma unroll
    for (int j = 0; j < 40; ++j) p[j] = pb[j];

    const float is = sh_is[g];
    float sn[16];
    #pragma unroll
    for (int chn = 0; chn < 16; ++chn)
        sn[chn] = (p[chn] - sh_mu[g][chn]) * is * sh_lws[chn] + sh_lbs[chn];
    #pragma unroll
    for (int b = 0; b < 16; ++b) {
        const float g0 = es0[b];
        #pragma unroll
        for (int chn = 0; chn < 16; ++chn) sn[chn] += g0 * sh_skip[b][chn];
    }
    #pragma unroll
    for (int o = 0; o < 16; ++o) {
        float a = sh_bes[o];
        #pragma unroll
        for (int chn = 0; chn < 16; ++chn) a += sn[chn] * sh_wes[chn][o];
        pb[o] = a;
    }
    const float iv = sh_iv[g];
    float vn[8][3];
    #pragma unroll
    for (int i = 0; i < 8; ++i) {
        const float f = iv * sh_lwv[i];
        vn[i][0] = p[16 + i*3 + 0] * f;
        vn[i][1] = p[16 + i*3 + 1] * f;
        vn[i][2] = p[16 + i*3 + 2] * f;
    }
    #pragma unroll
    for (int o = 0; o < 8; ++o) {
        float r0 = 0.0f, r1 = 0.0f, r2 = 0.0f;
        #pragma unroll
        for (int i = 0; i < 8; ++i) {
            const float w = sh_wev[i][o];
            r0 += vn[i][0] * w; r1 += vn[i][1] * w; r2 += vn[i][2] * w;
        }
        pb[16 + o*3 + 0] = r0;
        pb[16 + o*3 + 1] = r1;
        pb[16 + o*3 + 2] = r2;
    }
}

extern "C" void kernel_launch(void* const* d_in, const int* in_sizes, int n_in,
                              void* d_out, int out_size, void* d_ws, size_t ws_size,
                              hipStream_t stream)
{
    const float* node_fea  = (const float*)d_in[0];
    const float* edge_attr = (const float*)d_in[1];
    const int* edge_index  = (const int*)d_in[2];
    const int* xsp         = (const int*)d_in[3];
    const int* batch       = (const int*)d_in[4];
    const float* w_rh      = (const float*)d_in[5];
    const float* b_rh      = (const float*)d_in[6];
    const float* w_ro      = (const float*)d_in[7];
    const float* b_ro      = (const float*)d_in[8];
    const float* w_pre     = (const float*)d_in[9];
    const float* b_pre     = (const float*)d_in[10];
    const float* w_sc      = (const float*)d_in[11];
    const float* w_post_s  = (const float*)d_in[12];
    const float* b_post_s  = (const float*)d_in[13];
    const float* w_post_v  = (const float*)d_in[14];
    const float* ln_w_s    = (const float*)d_in[15];
    const float* ln_b_s    = (const float*)d_in[16];
    const float* ln_w_v    = (const float*)d_in[17];
    const float* w_skip    = (const float*)d_in[18];
    const float* w_edge_s  = (const float*)d_in[19];
    const float* b_edge_s  = (const float*)d_in[20];
    const float* w_edge_v  = (const float*)d_in[21];

    float* ws   = (float*)d_ws;          // 6144 floats bins + 32 ints binv (~24.7 KB)
    int*   binv = (int*)(ws + 6144);
    float* out  = (float*)d_out;

    k_init<<<1, 1024, 0, stream>>>(ws, binv);
    k_edge_heavy<<<2048, 256, 0, stream>>>(node_fea, edge_attr, edge_index, xsp,
        w_rh, b_rh, w_ro, b_ro, w_pre, b_pre, w_sc, w_post_s, b_post_s, w_post_v,
        binv, batch, ws, out);
    k_edge_final<<<256, 256, 0, stream>>>(out, ws, edge_attr, edge_index,
        batch, ln_w_s, ln_b_s, ln_w_v, w_skip, w_edge_s, b_edge_s, w_edge_v);
}

// Round 18
// 400.463 us; speedup vs baseline: 1.0207x; 1.0207x over previous
//
#include <hip/hip_runtime.h>

typedef unsigned short u16;
typedef unsigned int u32;
typedef __attribute__((ext_vector_type(8))) _Float16 half8;
typedef __attribute__((ext_vector_type(2))) __fp16 fp16x2;
typedef __attribute__((ext_vector_type(4))) float floatx4;

#define E_TOTAL 65536

__device__ __forceinline__ u32 pk16(float x0, float x1) {
    union { fp16x2 h; u32 u; } c;
    c.h = __builtin_amdgcn_cvt_pkrtz(x0, x1);
    return c.u;
}
union Frag8h { u32 u[4]; half8 v; };

// ws layout (floats): [0:6144] = 8 replicated 768-slot stat-bin arrays;
// ints [6144:6176] = binv.

// ---------------- Init: zero stat replicas + probe MFMA k-pairing (fused) ----------
__global__ __launch_bounds__(1024) void k_init(float* __restrict__ ws, int* __restrict__ binv) {
    const int tid = threadIdx.x;
    for (int i = tid; i < 6144; i += 1024) ws[i] = 0.0f;
    if (tid < 64) {
        const int lane = tid;
        const int q = lane >> 4;
        if (lane < 32) binv[lane] = lane;    // default identity (safety)
        half8 bfr;
        #pragma unroll
        for (int j = 0; j < 8; ++j) bfr[j] = (_Float16)(float)(q*8 + j + 1);
        #pragma unroll
        for (int s = 0; s < 32; ++s) {
            const int qa = s >> 3, ja = s & 7;
            half8 afr;
            #pragma unroll
            for (int j = 0; j < 8; ++j) afr[j] = (_Float16)0.0f;
            if (q == qa) afr[ja] = (_Float16)1.0f;
            floatx4 dc = {0.0f, 0.0f, 0.0f, 0.0f};
            dc = __builtin_amdgcn_mfma_f32_16x16x32_f16(afr, bfr, dc, 0, 0, 0);
            if (lane == 0) {
                const int sB = (int)(dc[0] + 0.5f) - 1;
                if (sB >= 0 && sB < 32) binv[sB] = s;
            }
        }
    }
}

// ---------------- Kernel 1: heavy conv, 64 edges/block, 512 threads -----------------
// One weight load feeds FOUR M=16 edge groups (L2 weight traffic 2GB -> 1GB, the
// measured dominant cost). 8 waves x 16 cols = 128-col chunk (1 tile/wave). Prefetch
// + fp16 MFMA + folded replicated stats carried over from R17.
__global__ __launch_bounds__(512) void k_edge_heavy(
    const float* __restrict__ node_fea, const float* __restrict__ edge_attr,
    const int* __restrict__ edge_index, const int* __restrict__ xsp,
    const float* __restrict__ w_rh, const float* __restrict__ b_rh,
    const float* __restrict__ w_ro, const float* __restrict__ b_ro,
    const float* __restrict__ w_pre, const float* __restrict__ b_pre,
    const float* __restrict__ w_sc, const float* __restrict__ w_post_s,
    const float* __restrict__ b_post_s, const float* __restrict__ w_post_v,
    const int* __restrict__ binv, const int* __restrict__ batch,
    float* __restrict__ ws_stats,
    float* __restrict__ out)
{
    __shared__ __align__(16) float sh_wt[64][130];   // 33280 B; prologue overlays here
    __shared__ float sh_sin[64][80];
    __shared__ float sh_vl[64][3][32];
    __shared__ float sh_acc[64][56];
    __shared__ float sh_y1[64][4];
    __shared__ int   sh_kmap[32];

    // Overlay (dead before first sh_wt write; disjoint):
    u16*   a_rbf = (u16*)&sh_wt[0][0];                     // [0,16384) B : 4 groups x 2048 u16
    u16*   a_h   = (u16*)((char*)&sh_wt[0][0] + 16384);    // [16384,24576) B : 4 x 1024 u16
    float* es0f  = (float*)((char*)&sh_wt[0][0] + 24576);  // [24576,28672) B : 64x16 f32

    const int tid = threadIdx.x;
    const int ed2 = tid >> 4, l16 = tid & 15;   // 32 edge-slots x 16 threads
    const int lane = tid & 63, w = tid >> 6;    // 8 waves
    const int quad = lane >> 4, l15 = lane & 15;

    if (tid < 32) sh_kmap[tid] = binv[tid];

    // ---- prologue over 2 halves (gg=0: edges 0..31, gg=1: edges 32..63) ----
    const float C128 = -0.5f * (127.0f/6.0f) * (127.0f/6.0f);
    const float S128 = 6.0f/127.0f;
    const float rs80 = 0.11180339887498949f;
    const float rs32 = 0.17677669529663689f;

    int niA, njA, niB, njB;
    float dA, dB;
    {
        const int eA = blockIdx.x * 64 + ed2;
        const int eB = eA + 32;
        niA = edge_index[eA]; njA = edge_index[E_TOTAL + eA];
        niB = edge_index[eB]; njB = edge_index[E_TOTAL + eB];
        const float4 eaA = *(const float4*)(edge_attr + 4*eA);
        const float4 eaB = *(const float4*)(edge_attr + 4*eB);
        dA = eaA.x; dB = eaB.x;
        const float invnA = 1.0f / (sqrtf(eaA.y*eaA.y + eaA.z*eaA.z + eaA.w*eaA.w) + 1e-12f);
        const float invnB = 1.0f / (sqrtf(eaB.y*eaB.y + eaB.z*eaB.z + eaB.w*eaB.w) + 1e-12f);
        if (l16 == 0) {
            sh_y1[ed2][0]    = 1.7320508075688772f * eaA.y * invnA;
            sh_y1[ed2][1]    = 1.7320508075688772f * eaA.z * invnA;
            sh_y1[ed2][2]    = 1.7320508075688772f * eaA.w * invnA;
            sh_y1[32+ed2][0] = 1.7320508075688772f * eaB.y * invnB;
            sh_y1[32+ed2][1] = 1.7320508075688772f * eaB.z * invnB;
            sh_y1[32+ed2][2] = 1.7320508075688772f * eaB.w * invnB;
        }
        // rbf -> fp16 A-fragments. group = e_local>>4, m = e_local&15.
        const int gA = ed2 >> 4, mA = ed2 & 15;
        const int gB = 2 + gA,   mB = mA;
        Frag8h tA, tB;
        #pragma unroll
        for (int r2 = 0; r2 < 4; ++r2) {
            const int b0i = l16*8 + 2*r2;
            const float u0 = dA - S128 * (float)b0i;
            const float u1 = dA - S128 * (float)(b0i + 1);
            const float v0 = dB - S128 * (float)b0i;
            const float v1 = dB - S128 * (float)(b0i + 1);
            tA.u[r2] = pk16(expf(C128*u0*u0), expf(C128*u1*u1));
            tB.u[r2] = pk16(expf(C128*v0*v0), expf(C128*v1*v1));
        }
        *(half8*)&a_rbf[gA*2048 + (l16*16 + mA)*8] = tA.v;
        *(half8*)&a_rbf[gB*2048 + (l16*16 + mB)*8] = tB.v;
        const float t0 = dA - 0.4f * (float)l16;
        const float t1 = dB - 0.4f * (float)l16;
        es0f[ed2*16 + l16]      = expf(-3.125f * t0 * t0);
        es0f[(32+ed2)*16 + l16] = expf(-3.125f * t1 * t1);

        const float* fiA = node_fea + (size_t)niA * 80;
        const float* fjA = node_fea + (size_t)njA * 80;
        sh_sin[ed2][2*l16+0]    = fiA[2*l16+0] * rs80;
        sh_sin[ed2][2*l16+1]    = fiA[2*l16+1] * rs80;
        sh_sin[ed2][32+2*l16+0] = fjA[2*l16+0] * rs80;
        sh_sin[ed2][32+2*l16+1] = fjA[2*l16+1] * rs80;
        const float* fiB = node_fea + (size_t)niB * 80;
        const float* fjB = node_fea + (size_t)njB * 80;
        sh_sin[32+ed2][2*l16+0]    = fiB[2*l16+0] * rs80;
        sh_sin[32+ed2][2*l16+1]    = fiB[2*l16+1] * rs80;
        sh_sin[32+ed2][32+2*l16+0] = fjB[2*l16+0] * rs80;
        sh_sin[32+ed2][32+2*l16+1] = fjB[2*l16+1] * rs80;
        #pragma unroll
        for (int c = 0; c < 3; ++c) {
            sh_vl[ed2][c][l16]         = fiA[32 + 3*l16 + c] * rs32;
            sh_vl[ed2][c][16 + l16]    = fjA[32 + 3*l16 + c] * rs32;
            sh_vl[32+ed2][c][l16]      = fiB[32 + 3*l16 + c] * rs32;
            sh_vl[32+ed2][c][16 + l16] = fjB[32 + 3*l16 + c] * rs32;
        }
    }
    const int giA = batch[niA];
    const int giB = batch[niB];
    for (int s = tid; s < 64*56; s += 512) (&sh_acc[0][0])[s] = 0.0f;
    __syncthreads();

    int km[8];
    u32 voff0[8], voff1[8];
    #pragma unroll
    for (int j = 0; j < 8; ++j) {
        km[j] = sh_kmap[quad*8 + j];
        voff0[j] = (u32)(km[j] * 3840 + l15);
        voff1[j] = voff0[j] + 32u * 3840u;
    }

    // edge_s + sc for both of this thread's edges (reads es0f overlay)
    float my_scA, my_scB;
    {
        const int o = l16;
        float esA = b_pre[o], scA = 0.0f;
        float esB = b_pre[o], scB = 0.0f;
        const int pA = 4*xsp[niA] + xsp[njA];
        const int pB = 4*xsp[niB] + xsp[njB];
        #pragma unroll
        for (int i = 0; i < 16; ++i) {
            const float g0 = es0f[ed2*16 + i];
            const float g1 = es0f[(32+ed2)*16 + i];
            esA += g0 * w_pre[i*16 + o];
            esB += g1 * w_pre[i*16 + o];
            scA += g0 * w_sc[(i*16 + pA)*16 + o];
            scB += g1 * w_sc[(i*16 + pB)*16 + o];
        }
        sh_sin[ed2][64 + o]    = esA * rs80;
        sh_sin[32+ed2][64 + o] = esB * rs80;
        my_scA = scA * 0.0625f;
        my_scB = scB * 0.0625f;
    }

    // h = silu(rbf @ w_rh + b_rh): wave quads {0-3}->groups 0,1; {4-7}->groups 2,3
    {
        const int wl = w & 3, gpair = w >> 2;
        const int G0 = gpair*2, G1 = G0 + 1;
        floatx4 h0 = {0.0f, 0.0f, 0.0f, 0.0f};
        floatx4 h1 = {0.0f, 0.0f, 0.0f, 0.0f};
        #pragma unroll
        for (int kk = 0; kk < 4; ++kk) {
            const half8 ag0 = *(const half8*)&a_rbf[G0*2048 + ((kk*4 + quad)*16 + l15)*8];
            const half8 ag1 = *(const half8*)&a_rbf[G1*2048 + ((kk*4 + quad)*16 + l15)*8];
            Frag8h bh;
            #pragma unroll
            for (int jj = 0; jj < 4; ++jj) {
                const float x0 = w_rh[(size_t)(kk*32 + km[2*jj+0])*64 + wl*16 + l15];
                const float x1 = w_rh[(size_t)(kk*32 + km[2*jj+1])*64 + wl*16 + l15];
                bh.u[jj] = pk16(x0, x1);
            }
            h0 = __builtin_amdgcn_mfma_f32_16x16x32_f16(ag0, bh.v, h0, 0, 0, 0);
            h1 = __builtin_amdgcn_mfma_f32_16x16x32_f16(ag1, bh.v, h1, 0, 0, 0);
        }
        const int hn = wl*16 + l15;
        const float bb = b_rh[hn];
        const int k8 = hn >> 3, j2 = hn & 7;
        #pragma unroll
        for (int r = 0; r < 4; ++r) {
            const int m = quad*4 + r;
            {
                const float x = h0[r] + bb;
                const float s = x / (1.0f + expf(-x));
                union { _Float16 h; u16 u; } cv; cv.h = (_Float16)s;
                a_h[G0*1024 + (k8*16 + m)*8 + j2] = cv.u;
            }
            {
                const float x = h1[r] + bb;
                const float s = x / (1.0f + expf(-x));
                union { _Float16 h; u16 u; } cv; cv.h = (_Float16)s;
                a_h[G1*1024 + (k8*16 + m)*8 + j2] = cv.u;
            }
        }
    }
    __syncthreads();

    // A-fragments for ALL 4 groups into registers (overlay dies after this point)
    const half8 aA0 = *(const half8*)&a_h[0*1024 + ((0*4 + quad)*16 + l15)*8];
    const half8 aA1 = *(const half8*)&a_h[0*1024 + ((1*4 + quad)*16 + l15)*8];
    const half8 aB0 = *(const half8*)&a_h[1*1024 + ((0*4 + quad)*16 + l15)*8];
    const half8 aB1 = *(const half8*)&a_h[1*1024 + ((1*4 + quad)*16 + l15)*8];
    const half8 aC0 = *(const half8*)&a_h[2*1024 + ((0*4 + quad)*16 + l15)*8];
    const half8 aC1 = *(const half8*)&a_h[2*1024 + ((1*4 + quad)*16 + l15)*8];
    const half8 aD0 = *(const half8*)&a_h[3*1024 + ((0*4 + quad)*16 + l15)*8];
    const half8 aD1 = *(const half8*)&a_h[3*1024 + ((1*4 + quad)*16 + l15)*8];

    // Prefetch chunk 0: wave w -> col-tile ch*8 + w  (16 floats + 1 bias)
    float pf[16];
    float pbias;
    {
        const int sgct = __builtin_amdgcn_readfirstlane(w);
        const float* bp = w_ro + sgct*16;
        #pragma unroll
        for (int j = 0; j < 8; ++j) {
            pf[j]     = bp[voff0[j]];
            pf[8 + j] = bp[voff1[j]];
        }
        pbias = b_ro[sgct*16 + l15];
    }

    // -------- main loop: 30 chunks x 128 cols; 1 tile/wave; prefetch under consumers --
    for (int ch = 0; ch < 30; ++ch) {
        const int coff = ch * 128;
        Frag8h b0, b1;
        #pragma unroll
        for (int jj = 0; jj < 4; ++jj) {
            b0.u[jj] = pk16(pf[2*jj],     pf[2*jj+1]);
            b1.u[jj] = pk16(pf[8 + 2*jj], pf[8 + 2*jj+1]);
        }
        floatx4 accA = {0,0,0,0}, accB = {0,0,0,0}, accC = {0,0,0,0}, accD = {0,0,0,0};
        accA = __builtin_amdgcn_mfma_f32_16x16x32_f16(aA0, b0.v, accA, 0, 0, 0);
        accA = __builtin_amdgcn_mfma_f32_16x16x32_f16(aA1, b1.v, accA, 0, 0, 0);
        accB = __builtin_amdgcn_mfma_f32_16x16x32_f16(aB0, b0.v, accB, 0, 0, 0);
        accB = __builtin_amdgcn_mfma_f32_16x16x32_f16(aB1, b1.v, accB, 0, 0, 0);
        accC = __builtin_amdgcn_mfma_f32_16x16x32_f16(aC0, b0.v, accC, 0, 0, 0);
        accC = __builtin_amdgcn_mfma_f32_16x16x32_f16(aC1, b1.v, accC, 0, 0, 0);
        accD = __builtin_amdgcn_mfma_f32_16x16x32_f16(aD0, b0.v, accD, 0, 0, 0);
        accD = __builtin_amdgcn_mfma_f32_16x16x32_f16(aD1, b1.v, accD, 0, 0, 0);
        const float bsv = pbias;
        __syncthreads();   // previous chunk's consumers done with sh_wt
        {
            const int col = w*16 + l15;
            #pragma unroll
            for (int r = 0; r < 4; ++r) {
                sh_wt[ 0 + quad*4 + r][col] = accA[r] + bsv;
                sh_wt[16 + quad*4 + r][col] = accB[r] + bsv;
                sh_wt[32 + quad*4 + r][col] = accC[r] + bsv;
                sh_wt[48 + quad*4 + r][col] = accD[r] + bsv;
            }
        }
        __syncthreads();

        // prefetch chunk ch+1 (in flight during consumers)
        if (ch < 29) {
            const int sgct = __builtin_amdgcn_readfirstlane((ch+1)*8 + w);
            const float* bp = w_ro + sgct*16;
            #pragma unroll
            for (int j = 0; j < 8; ++j) {
                pf[j]     = bp[voff0[j]];
                pf[8 + j] = bp[voff1[j]];
            }
            pbias = b_ro[sgct*16 + l15];
        }

        if (ch < 15) {          // w1: cols 0..1920, 24-wide -> s_conv (dynamic bounds)
            for (int idx = tid; idx < 1536; idx += 512) {
                const int eo = idx / 24, o = idx % 24;
                const int i0 = (coff > o) ? (coff - o + 23) / 24 : 0;
                int i1 = (coff + 128 - o + 23) / 24; if (i1 > 80) i1 = 80;
                float a = 0.0f;
                for (int i = i0; i < i1; ++i)
                    a += sh_sin[eo][i] * sh_wt[eo][i*24 + o - coff];
                sh_acc[eo][o] += a;
            }
        } else if (ch < 20) {   // w2: 16 rows x 8 per chunk (STATIC)
            const int ib = (ch - 15) * 16;
            for (int idx = tid; idx < 512; idx += 512) {
                const int eo = idx >> 3, o = idx & 7;
                float a = 0.0f;
                #pragma unroll
                for (int i = 0; i < 16; ++i)
                    a += sh_sin[eo][ib + i] * sh_wt[eo][i*8 + o];
                sh_acc[eo][24 + o] += a;
            }
        } else if (ch < 22) {   // w3: 16 rows x 8 per chunk, left = v_in[:,c] (STATIC)
            const int ib = (ch - 20) * 16;
            for (int idx = tid; idx < 1536; idx += 512) {
                const int eo = idx / 24, rem = idx % 24;
                const int o = rem / 3, cc = rem % 3;
                float a = 0.0f;
                #pragma unroll
                for (int i = 0; i < 16; ++i)
                    a += sh_vl[eo][cc][ib + i] * sh_wt[eo][i*8 + o];
                sh_acc[eo][32 + o*3 + cc] += a;
            }
        } else if (ch < 28) {   // w4: cols 2816..3584, 24-wide, q inline (dynamic)
            const int rel = coff - 2816;
            for (int idx = tid; idx < 1536; idx += 512) {
                const int eo = idx / 24, o = idx % 24;
                const int i0 = (rel > o) ? (rel - o + 23) / 24 : 0;
                int i1 = (rel + 128 - o + 23) / 24; if (i1 > 32) i1 = 32;
                const float Ya = sh_y1[eo][0], Yb = sh_y1[eo][1], Yc = sh_y1[eo][2];
                float a = 0.0f;
                for (int i = i0; i < i1; ++i) {
                    const float qv = sh_vl[eo][0][i]*Ya + sh_vl[eo][1][i]*Yb
                                   + sh_vl[eo][2][i]*Yc;
                    a += qv * sh_wt[eo][i*24 + o - rel];
                }
                sh_acc[eo][o] += a * 0.57735026918962573f;
            }
        } else {                // w5: 16 rows x 8 per chunk, cross inline (STATIC)
            const int ib = (ch - 28) * 16;
            for (int idx = tid; idx < 1536; idx += 512) {
                const int eo = idx / 24, rem = idx % 24;
                const int o = rem / 3, cc = rem % 3;
                const int c1 = (cc < 2) ? cc + 1 : 0;
                const int c2 = (c1 < 2) ? c1 + 1 : 0;
                const float Yp = sh_y1[eo][c2];
                const float Ym = sh_y1[eo][c1];
                float a = 0.0f;
                #pragma unroll
                for (int i = 0; i < 16; ++i)
                    a += (sh_vl[eo][c1][ib+i]*Yp - sh_vl[eo][c2][ib+i]*Ym) * sh_wt[eo][i*8 + o];
                sh_acc[eo][32 + o*3 + cc] += a * 0.70710678118654746f;
            }
        }
    }
    __syncthreads();

    // -------- epilogue: outputs + folded stats (LDS bins overlay; 8-way replica) ----
    float* bins = &sh_wt[0][0];   // 768 floats; sh_wt dead after final barrier
    for (int s = tid; s < 768; s += 512) bins[s] = 0.0f;
    __syncthreads();

    #pragma unroll
    for (int gg = 0; gg < 2; ++gg) {
        const int er = gg*32 + ed2;
        const int e  = blockIdx.x * 64 + er;
        const int gi = (gg == 0) ? giA : giB;
        const float msc = (gg == 0) ? my_scA : my_scB;
        {
            const int o = l16;
            float a = b_post_s[o] + msc;
            #pragma unroll
            for (int i = 0; i < 16; ++i) {
                const float sv = sh_acc[er][i];
                a += (sv / (1.0f + expf(-sv))) * w_post_s[i*16 + o];
            }
            out[(size_t)e*40 + o] = a;
            atomicAdd(&bins[gi*48 + o], a);
            atomicAdd(&bins[gi*48 + 16 + o], a*a);
            if (o == 0) atomicAdd(&bins[gi*48 + 40], 1.0f);
        }
        if (l16 < 8) {
            const int o = l16;
            const float Ya = sh_y1[er][0], Yb = sh_y1[er][1], Yc = sh_y1[er][2];
            float r0 = 0.0f, r1 = 0.0f, r2 = 0.0f;
            #pragma unroll
            for (int i = 0; i < 8; ++i) {
                const float gt = 1.0f / (1.0f + expf(-sh_acc[er][16 + i]));
                const float a2 = sh_acc[er][24 + i];
                const float ww = w_post_v[i*8 + o];
                r0 += (a2*Ya + sh_acc[er][32 + i*3 + 0]) * gt * ww;
                r1 += (a2*Yb + sh_acc[er][32 + i*3 + 1]) * gt * ww;
                r2 += (a2*Yc + sh_acc[er][32 + i*3 + 2]) * gt * ww;
            }
            out[(size_t)e*40 + 16 + o*3 + 0] = r0;
            out[(size_t)e*40 + 16 + o*3 + 1] = r1;
            out[(size_t)e*40 + 16 + o*3 + 2] = r2;
            atomicAdd(&bins[gi*48 + 32 + o], r0*r0 + r1*r1 + r2*r2);
        }
    }
    __syncthreads();
    {
        float* rep = ws_stats + (blockIdx.x & 7) * 768;   // 8-way replicated targets
        for (int s = tid; s < 768; s += 512) {
            const float x = bins[s];
            if (x != 0.0f) atomicAdd(&rep[s], x);
        }
    }
}

// ---------------- Kernel 4: stats-finalize (sums 8 replicas) + LN + projections -----
__global__ __launch_bounds__(256) void k_edge_final(
    float* buf, const float* __restrict__ ws,
    const float* __restrict__ edge_attr, const int* __restrict__ edge_index,
    const int* __restrict__ batch,
    const float* __restrict__ ln_w_s, const float* __restrict__ ln_b_s,
    const float* __restrict__ ln_w_v, const float* __restrict__ w_skip,
    const float* __restrict__ w_edge_s, const float* __restrict__ b_edge_s,
    const float* __restrict__ w_edge_v)
{
    __shared__ float sh_mu[16][16];
    __shared__ float sh_is[16], sh_iv[16];
    __shared__ float sh_lws[16], sh_lbs[16], sh_lwv[8];
    __shared__ float sh_skip[16][16], sh_wes[16][16], sh_bes[16], sh_wev[8][8];
    const int tid = threadIdx.x;
    if (tid < 16) {
        const int g = tid;
        float sums[41];
        #pragma unroll
        for (int k = 0; k < 41; ++k) sums[k] = 0.0f;
        for (int r = 0; r < 8; ++r) {
            const float* rep = ws + r*768 + g*48;
            for (int chn = 0; chn < 16; ++chn) { sums[chn] += rep[chn]; sums[16+chn] += rep[16+chn]; }
            for (int o = 0; o < 8; ++o) sums[32+o] += rep[32+o];
            sums[40] += rep[40];
        }
        float cnt = sums[40]; if (cnt < 1.0f) cnt = 1.0f;
        const float ic = 1.0f / cnt;
        float vs = 0.0f;
        for (int chn = 0; chn < 16; ++chn) {
            const float mu = sums[chn] * ic;
            sh_mu[g][chn] = mu;
            vs += sums[16+chn] * ic - mu * mu;
        }
        if (vs < 0.0f) vs = 0.0f;
        sh_is[g] = 1.0f / sqrtf(vs * (1.0f/16.0f) + 1e-5f);
        float vv = 0.0f;
        for (int o = 0; o < 8; ++o) vv += sums[32+o];
        vv = vv * ic * (1.0f/3.0f) * (1.0f/8.0f);
        sh_iv[g] = 1.0f / sqrtf(vv + 1e-5f);
    }
    sh_skip[tid >> 4][tid & 15] = w_skip[tid];
    sh_wes[tid >> 4][tid & 15]  = w_edge_s[tid];
    if (tid < 16) {
        sh_lws[tid] = ln_w_s[tid];
        sh_lbs[tid] = ln_b_s[tid];
        sh_bes[tid] = b_edge_s[tid];
    }
    if (tid < 8)  sh_lwv[tid] = ln_w_v[tid];
    if (tid < 64) sh_wev[tid >> 3][tid & 7] = w_edge_v[tid];
    __syncthreads();

    const int e = blockIdx.x * 256 + tid;
    const int g = batch[edge_index[e]];
    const float d = edge_attr[4*e];
    float es0[16];
    #pragma unroll
    for (int b = 0; b < 16; ++b) {
        const float t = d - 0.4f * (float)b;
        es0[b] = expf(-3.125f * t * t);
    }
    float p[40];
    float* pb = buf + (size_t)e * 40;
    #pragma unroll
    for (int j = 0; j < 40; ++j) p[j] = pb[j];

    const float is = sh_is[g];
    float sn[16];
    #pragma unroll
    for (int chn = 0; chn < 16; ++chn)
        sn[chn] = (p[chn] - sh_mu[g][chn]) * is * sh_lws[chn] + sh_lbs[chn];
    #pragma unroll
    for (int b = 0; b < 16; ++b) {
        const float g0 = es0[b];
        #pragma unroll
        for (int chn = 0; chn < 16; ++chn) sn[chn] += g0 * sh_skip[b][chn];
    }
    #pragma unroll
    for (int o = 0; o < 16; ++o) {
        float a = sh_bes[o];
        #pragma unroll
        for (int chn = 0; chn < 16; ++chn) a += sn[chn] * sh_wes[chn][o];
        pb[o] = a;
    }
    const float iv = sh_iv[g];
    float vn[8][3];
    #pragma unroll
    for (int i = 0; i < 8; ++i) {
        const float f = iv * sh_lwv[i];
        vn[i][0] = p[16 + i*3 + 0] * f;
        vn[i][1] = p[16 + i*3 + 1] * f;
        vn[i][2] = p[16 + i*3 + 2] * f;
    }
    #pragma unroll
    for (int o = 0; o < 8; ++o) {
        float r0 = 0.0f, r1 = 0.0f, r2 = 0.0f;
        #pragma unroll
        for (int i = 0; i < 8; ++i) {
            const float w = sh_wev[i][o];
            r0 += vn[i][0] * w; r1 += vn[i][1] * w; r2 += vn[i][2] * w;
        }
        pb[16 + o*3 + 0] = r0;
        pb[16 + o*3 + 1] = r1;
        pb[16 + o*3 + 2] = r2;
    }
}

extern "C" void kernel_launch(void* const* d_in, const int* in_sizes, int n_in,
                              void* d_out, int out_size, void* d_ws, size_t ws_size,
                              hipStream_t stream)
{
    const float* node_fea  = (const float*)d_in[0];
    const float* edge_attr = (const float*)d_in[1];
    const int* edge_index  = (const int*)d_in[2];
    const int* xsp         = (const int*)d_in[3];
    const int* batch       = (const int*)d_in[4];
    const float* w_rh      = (const float*)d_in[5];
    const float* b_rh      = (const float*)d_in[6];
    const float* w_ro      = (const float*)d_in[7];
    const float* b_ro      = (const float*)d_in[8];
    const float* w_pre     = (const float*)d_in[9];
    const float* b_pre     = (const float*)d_in[10];
    const float* w_sc      = (const float*)d_in[11];
    const float* w_post_s  = (const float*)d_in[12];
    const float* b_post_s  = (const float*)d_in[13];
    const float* w_post_v  = (const float*)d_in[14];
    const float* ln_w_s    = (const float*)d_in[15];
    const float* ln_b_s    = (const float*)d_in[16];
    const float* ln_w_v    = (const float*)d_in[17];
    const float* w_skip    = (const float*)d_in[18];
    const float* w_edge_s  = (const float*)d_in[19];
    const float* b_edge_s  = (const float*)d_in[20];
    const float* w_edge_v  = (const float*)d_in[21];

    float* ws   = (float*)d_ws;          // 6144 floats bins + 32 ints binv (~24.7 KB)
    int*   binv = (int*)(ws + 6144);
    float* out  = (float*)d_out;

    k_init<<<1, 1024, 0, stream>>>(ws, binv);
    k_edge_heavy<<<1024, 512, 0, stream>>>(node_fea, edge_attr, edge_index, xsp,
        w_rh, b_rh, w_ro, b_ro, w_pre, b_pre, w_sc, w_post_s, b_post_s, w_post_v,
        binv, batch, ws, out);
    k_edge_final<<<256, 256, 0, stream>>>(out, ws, edge_attr, edge_index,
        batch, ln_w_s, ln_b_s, ln_w_v, w_skip, w_edge_s, b_edge_s, w_edge_v);
}